// Round 1
// 366.210 us; speedup vs baseline: 1.0284x; 1.0284x over previous
//
#include <hip/hip_runtime.h>
#include <stdint.h>

typedef unsigned short u16;
typedef short v8s __attribute__((ext_vector_type(8)));
typedef float v4f __attribute__((ext_vector_type(4)));

#define BM 128
#define BN 128
#define BK 32

__device__ __forceinline__ float b2f(u16 b) {
  union { unsigned u; float f; } x; x.u = ((unsigned)b) << 16; return x.f;
}
__device__ __forceinline__ u16 f2b(float f) {
  union { float f; unsigned u; } x; x.f = f;
  unsigned r = x.u + 0x7fffu + ((x.u >> 16) & 1u);
  return (u16)(r >> 16);
}

// global -> LDS async DMA, 16B per lane (m97 idiom): LDS dst wave-uniform
// base, HW writes lane i at base + i*16B.
__device__ __forceinline__ void async_copy16(const void* g, void* lds) {
  __builtin_amdgcn_global_load_lds(
      (const __attribute__((address_space(1))) void*)g,
      (__attribute__((address_space(3))) void*)(uint32_t)(uintptr_t)lds,
      16, 0, 0);
}

// XCD-aware bijective block swizzle (T1, m204 formula): default dispatch
// round-robins consecutive ids across the 8 XCDs; remap so each XCD owns a
// contiguous chunk of the flattened grid -> neighbor blocks sharing A/W
// panels hit the same per-XCD L2.
__device__ __forceinline__ void xcd_swz(int& bx, int& by) {
  const int gx = gridDim.x;
  const int nwg = gx * gridDim.y;
  const int ord = blockIdx.y * gx + blockIdx.x;
  const int q = nwg >> 3, r = nwg & 7;
  const int xcd = ord & 7, local = ord >> 3;
  const int base = xcd < r ? xcd * (q + 1) : r * (q + 1) + (xcd - r) * q;
  const int s = base + local;
  bx = s % gx;
  by = s / gx;
}

// fused fp32 -> bf16 for q,k,v (grid.y selects tensor), 8 elems/thread
__global__ __launch_bounds__(256) void cvt3_kernel(
    const float* __restrict__ i0, const float* __restrict__ i1,
    const float* __restrict__ i2, u16* __restrict__ o0, u16* __restrict__ o1,
    u16* __restrict__ o2, int n) {
  const int z = blockIdx.y;
  const float* in = z == 0 ? i0 : (z == 1 ? i1 : i2);
  u16* out = z == 0 ? o0 : (z == 1 ? o1 : o2);
  const int i = (blockIdx.x * 256 + threadIdx.x) * 8;
  if (i >= n) return;
  v4f a = *(const v4f*)(in + i);
  v4f b = *(const v4f*)(in + i + 4);
  v8s o;
#pragma unroll
  for (int j = 0; j < 4; j++) o[j] = (short)f2b(a[j]);
#pragma unroll
  for (int j = 0; j < 4; j++) o[4 + j] = (short)f2b(b[j]);
  *(v8s*)(out + i) = o;
}

// fused fp32 -> bf16 for the 4 weight matrices (grid.y selects)
__global__ __launch_bounds__(256) void cvt4_kernel(
    const float* __restrict__ i0, const float* __restrict__ i1,
    const float* __restrict__ i2, const float* __restrict__ i3,
    u16* __restrict__ o0, u16* __restrict__ o1, u16* __restrict__ o2,
    u16* __restrict__ o3, int n) {
  const int z = blockIdx.y;
  const float* in = z == 0 ? i0 : (z == 1 ? i1 : (z == 2 ? i2 : i3));
  u16* out = z == 0 ? o0 : (z == 1 ? o1 : (z == 2 ? o2 : o3));
  const int i = (blockIdx.x * 256 + threadIdx.x) * 8;
  if (i >= n) return;
  v4f a = *(const v4f*)(in + i);
  v4f b = *(const v4f*)(in + i + 4);
  v8s o;
#pragma unroll
  for (int j = 0; j < 4; j++) o[j] = (short)f2b(a[j]);
#pragma unroll
  for (int j = 0; j < 4; j++) o[4 + j] = (short)f2b(b[j]);
  *(v8s*)(out + i) = o;
}

// Shared GEMM body: C[m,n] = sum_k A[m,k]*B[n,k] (+bias[n]).
// A: lda-strided, B: ldb-strided, bf16 bits. 128x128 tile, BK=32, 4 waves.
template <bool HAS_BIAS, bool CAUSAL_K, bool OUT_F32>
__device__ __forceinline__ void gemm_body(
    const u16* __restrict__ A, int lda, const u16* __restrict__ Bm, int ldb,
    void* __restrict__ Cout_, int ldc, long cbase,
    const float* __restrict__ bias, int K, int m0, int n0) {
  __shared__ u16 ldsA[BM * BK];
  __shared__ u16 ldsB[BN * BK];

  const int tid = threadIdx.x;
  const int wave = tid >> 6, lane = tid & 63;
  const int wm = (wave >> 1) * 64, wn = (wave & 1) * 64;
  const int lrow = lane & 15, quad = lane >> 4;

  v4f acc[4][4];
#pragma unroll
  for (int i = 0; i < 4; i++)
#pragma unroll
    for (int j = 0; j < 4; j++) acc[i][j] = v4f{0.f, 0.f, 0.f, 0.f};

  int Keff = K;
  if (CAUSAL_K) {
    int ke = m0 + BM;
    Keff = ke < K ? ke : K;
  }

  const int r0 = tid >> 2;       // rows 0..63
  const int c0 = (tid & 3) * 8;  // k-offset 0/8/16/24
  const u16* pA0 = A + (long)(m0 + r0) * lda + c0;
  const u16* pA1 = A + (long)(m0 + 64 + r0) * lda + c0;
  const u16* pB0 = Bm + (long)(n0 + r0) * ldb + c0;
  const u16* pB1 = Bm + (long)(n0 + 64 + r0) * ldb + c0;
  u16* dA0 = ldsA + wave * 512;
  u16* dA1 = ldsA + 2048 + wave * 512;
  u16* dB0 = ldsB + wave * 512;
  u16* dB1 = ldsB + 2048 + wave * 512;

  for (int k0 = 0; k0 < Keff; k0 += BK) {
    async_copy16(pA0 + k0, dA0);
    async_copy16(pA1 + k0, dA1);
    async_copy16(pB0 + k0, dB0);
    async_copy16(pB1 + k0, dB1);
    __syncthreads();

    v8s af[4], bfr[4];
#pragma unroll
    for (int mt = 0; mt < 4; mt++)
      af[mt] = *(const v8s*)&ldsA[(wm + mt * 16 + lrow) * BK + quad * 8];
#pragma unroll
    for (int nt = 0; nt < 4; nt++)
      bfr[nt] = *(const v8s*)&ldsB[(wn + nt * 16 + lrow) * BK + quad * 8];
#pragma unroll
    for (int mt = 0; mt < 4; mt++)
#pragma unroll
      for (int nt = 0; nt < 4; nt++)
        acc[mt][nt] = __builtin_amdgcn_mfma_f32_16x16x32_bf16(
            af[mt], bfr[nt], acc[mt][nt], 0, 0, 0);
    __syncthreads();
  }

  // epilogue: C/D layout col = lane&15, row = quad*4 + i (m89-verified)
#pragma unroll
  for (int mt = 0; mt < 4; mt++) {
    const int rowBase = m0 + wm + mt * 16 + quad * 4;
#pragma unroll
    for (int nt = 0; nt < 4; nt++) {
      const int col = n0 + wn + nt * 16 + lrow;
      float bv = 0.f;
      if (HAS_BIAS) bv = bias[col];
#pragma unroll
      for (int i = 0; i < 4; i++) {
        const long idx = cbase + (long)(rowBase + i) * ldc + col;
        const float val = acc[mt][nt][i] + bv;
        if (OUT_F32)
          ((float*)Cout_)[idx] = val;
        else
          ((u16*)Cout_)[idx] = f2b(val);
      }
    }
  }
}

// fused Q/K/V projections: grid.z = {0,1,2} selects (x, W, bias, out)
__global__ __launch_bounds__(256, 4) void qkv_gemm_kernel(
    const u16* __restrict__ a0, const u16* __restrict__ a1,
    const u16* __restrict__ a2, const u16* __restrict__ w0,
    const u16* __restrict__ w1, const u16* __restrict__ w2,
    const float* __restrict__ b0, const float* __restrict__ b1,
    const float* __restrict__ b2, u16* __restrict__ c0, u16* __restrict__ c1,
    u16* __restrict__ c2, int C) {
  const int z = blockIdx.z;
  const u16* A = z == 0 ? a0 : (z == 1 ? a1 : a2);
  const u16* W = z == 0 ? w0 : (z == 1 ? w1 : w2);
  const float* bias = z == 0 ? b0 : (z == 1 ? b1 : b2);
  u16* Cp = z == 0 ? c0 : (z == 1 ? c1 : c2);
  int bx, by;
  xcd_swz(bx, by);
  gemm_body<true, false, false>(A, C, W, C, Cp, C, 0,
                                bias, C, by * BM, bx * BN);
}

// generic batched GEMM (strided over grid.z)
template <bool HAS_BIAS, bool CAUSAL_SKIP, bool CAUSAL_K, bool OUT_F32>
__global__ __launch_bounds__(256, 4) void gemm_bt_kernel(
    const u16* __restrict__ A, int lda, long sA,
    const u16* __restrict__ Bm, int ldb, long sB,
    void* __restrict__ Cout_, int ldc, long sC,
    const float* __restrict__ bias, int K) {
  int bx, by;
  xcd_swz(bx, by);
  const int m0 = by * BM;
  const int n0 = bx * BN;
  if (CAUSAL_SKIP && n0 > m0) return;
  const int z = blockIdx.z;
  gemm_body<HAS_BIAS, CAUSAL_K, OUT_F32>(
      A + (long)z * sA, lda, Bm + (long)z * sB, ldb, Cout_, ldc,
      (long)z * sC, bias, K, m0, n0);
}

// Vp [B][T][C] -> VpT [B][C][T], 64x64 LDS tiles
__global__ __launch_bounds__(256) void transpose_kernel(
    const u16* __restrict__ in, u16* __restrict__ out) {
  __shared__ u16 tile[64][72];
  const int b = blockIdx.z;
  const int d0 = blockIdx.x * 64;  // C dim
  const int t0 = blockIdx.y * 64;  // T dim
  const u16* ip = in + (long)b * 2048 * 1024;
  u16* op = out + (long)b * 1024 * 2048;
  const int tid = threadIdx.x;
  const int tl = tid >> 2;
  const int dl = (tid & 3) * 16;
  const u16* src = ip + (long)(t0 + tl) * 1024 + d0 + dl;
  *(v8s*)&tile[tl][dl] = *(const v8s*)src;
  *(v8s*)&tile[tl][dl + 8] = *(const v8s*)(src + 8);
  __syncthreads();
  const int dd = tid >> 2;
  const int tt = (tid & 3) * 16;
  u16* dst = op + (long)(d0 + dd) * 2048 + t0 + tt;
  v8s o0, o1;
#pragma unroll
  for (int j = 0; j < 8; j++) o0[j] = (short)tile[tt + j][dd];
#pragma unroll
  for (int j = 0; j < 8; j++) o1[j] = (short)tile[tt + 8 + j][dd];
  *(v8s*)dst = o0;
  *(v8s*)(dst + 8) = o1;
}

// in-place causal softmax: P[j] = exp(s*scale - m)/sum for j<=i, else 0.
// Loads only j <= i (upper-triangle S blocks were never written -> don't
// fetch them); stores only j < Lw = ceil((i+1)/128)*128 (PV's CAUSAL_K
// reads exactly that many columns).
__global__ __launch_bounds__(256) void softmax_kernel(u16* __restrict__ S) {
  const float scale = 0.03125f;  // 1/sqrt(1024)
  const int i = blockIdx.x, b = blockIdx.y;
  const int tid = threadIdx.x;
  u16* row = S + ((long)b * 2048 + (long)i) * 2048;
  const int jb = tid * 8;
  const int Lw = ((i >> 7) + 1) << 7;  // write length (multiple of BK*4)
  v8s raw = {0, 0, 0, 0, 0, 0, 0, 0};
  if (jb <= i) raw = *(const v8s*)&row[jb];
  float v[8];
  float m = -1e30f;
#pragma unroll
  for (int jj = 0; jj < 8; jj++) {
    float x = (jb + jj <= i) ? b2f((u16)raw[jj]) * scale : -1e30f;
    v[jj] = x;
    m = fmaxf(m, x);
  }
#pragma unroll
  for (int off = 32; off; off >>= 1) m = fmaxf(m, __shfl_xor(m, off));
  __shared__ float red[4], red2[4];
  const int wave = tid >> 6, lane = tid & 63;
  if (lane == 0) red[wave] = m;
  __syncthreads();
  m = fmaxf(fmaxf(red[0], red[1]), fmaxf(red[2], red[3]));
  float s = 0.f, p[8];
#pragma unroll
  for (int jj = 0; jj < 8; jj++) {
    float e = (v[jj] > -1e29f) ? __expf(v[jj] - m) : 0.f;
    p[jj] = e;
    s += e;
  }
#pragma unroll
  for (int off = 32; off; off >>= 1) s += __shfl_xor(s, off);
  if (lane == 0) red2[wave] = s;
  __syncthreads();
  s = red2[0] + red2[1] + red2[2] + red2[3];
  const float inv = 1.0f / s;
  v8s outv;
#pragma unroll
  for (int jj = 0; jj < 8; jj++) outv[jj] = (short)f2b(p[jj] * inv);
  if (jb < Lw) *(v8s*)&row[jb] = outv;
}

extern "C" void kernel_launch(void* const* d_in, const int* in_sizes, int n_in,
                              void* d_out, int out_size, void* d_ws,
                              size_t ws_size, hipStream_t stream) {
  const float* q = (const float*)d_in[0];
  const float* k = (const float*)d_in[1];
  const float* v = (const float*)d_in[2];
  const float* Wq = (const float*)d_in[3];
  const float* bq = (const float*)d_in[4];
  const float* Wk = (const float*)d_in[5];
  const float* bk = (const float*)d_in[6];
  const float* Wv = (const float*)d_in[7];
  const float* bv = (const float*)d_in[8];
  const float* Wff = (const float*)d_in[9];
  const float* bff = (const float*)d_in[10];
  float* out = (float*)d_out;

  const int B = 4, T = 2048, C = 1024, M = B * T;  // M = 8192
  const size_t MC = (size_t)M * C;                 // 8.4M elems
  const size_t CC = (size_t)C * C;                 // 1M elems
  u16* ws = (u16*)d_ws;
  u16* qb = ws;              // [M*C]  (later: S overlays qb+kb)
  u16* kb = qb + MC;
  u16* vb = kb + MC;
  u16* Wqb = vb + MC;        // [C*C] x4
  u16* Wkb = Wqb + CC;
  u16* Wvb = Wkb + CC;
  u16* Wffb = Wvb + CC;
  u16* Qp = Wffb + CC;       // [B][T][C]
  u16* Kp = Qp + MC;
  u16* Vp = Kp + MC;         // reused as attn
  u16* VpT = Vp + MC;        // [B][C][T]
  u16* S = qb;               // [B][T][T], overlays qb+kb (dead by then)
  u16* attn = Vp;            // Vp dead after transpose

  dim3 blk(256);
  // fp32 -> bf16 conversions (2 fused launches)
  cvt3_kernel<<<dim3((int)(MC / 2048), 3), blk, 0, stream>>>(
      q, k, v, qb, kb, vb, (int)MC);
  cvt4_kernel<<<dim3((int)(CC / 2048), 4), blk, 0, stream>>>(
      Wq, Wk, Wv, Wff, Wqb, Wkb, Wvb, Wffb, (int)CC);

  // fused Q/K/V projections (grid 8 x 64 x 3 = 1536 blocks)
  qkv_gemm_kernel<<<dim3(C / BN, M / BM, 3), blk, 0, stream>>>(
      qb, kb, vb, Wqb, Wkb, Wvb, bq, bk, bv, Qp, Kp, Vp, C);
  // V transpose for the PV GEMM
  transpose_kernel<<<dim3(C / 64, T / 64, B), blk, 0, stream>>>(Vp, VpT);
  // scores S = Qp @ Kp^T per batch (skip blocks above diagonal)
  gemm_bt_kernel<false, true, false, false>
      <<<dim3(T / BN, T / BM, B), blk, 0, stream>>>(
          Qp, C, (long)T * C, Kp, C, (long)T * C, S, T, (long)T * T,
          nullptr, C);
  // causal softmax in-place -> P
  softmax_kernel<<<dim3(T, B), blk, 0, stream>>>(S);
  // attn = P @ V per batch (K limited to diagonal); attn overwrites Vp
  gemm_bt_kernel<false, false, true, false>
      <<<dim3(C / BN, T / BM, B), blk, 0, stream>>>(
          S, T, (long)T * T, VpT, T, (long)C * T, attn, C, (long)T * C,
          nullptr, T);
  // out = attn @ Wff.T + bff  (fp32 out)
  gemm_bt_kernel<true, false, false, true>
      <<<dim3(C / BN, M / BM, 1), blk, 0, stream>>>(
          attn, C, 0, Wffb, C, 0, out, C, 0, bff, C);
}

// Round 2
// 327.870 us; speedup vs baseline: 1.1486x; 1.1169x over previous
//
#include <hip/hip_runtime.h>
#include <stdint.h>

typedef unsigned short u16;
typedef short v8s __attribute__((ext_vector_type(8)));
typedef float v4f __attribute__((ext_vector_type(4)));

#define BM 128
#define BN 128
#define BK 64

__device__ __forceinline__ float b2f(u16 b) {
  union { unsigned u; float f; } x; x.u = ((unsigned)b) << 16; return x.f;
}
__device__ __forceinline__ u16 f2b(float f) {
  union { float f; unsigned u; } x; x.f = f;
  unsigned r = x.u + 0x7fffu + ((x.u >> 16) & 1u);
  return (u16)(r >> 16);
}

// global -> LDS async DMA, 16B per lane (m97 idiom): LDS dst wave-uniform
// base, HW writes lane i at base + i*16B.
__device__ __forceinline__ void async_copy16(const void* g, void* lds) {
  __builtin_amdgcn_global_load_lds(
      (const __attribute__((address_space(1))) void*)g,
      (__attribute__((address_space(3))) void*)(uint32_t)(uintptr_t)lds,
      16, 0, 0);
}

// XCD-aware bijective block swizzle (T1, m204): each XCD owns a contiguous
// chunk of the flattened grid. For dense (non-causal) GEMMs.
__device__ __forceinline__ void xcd_swz(int& bx, int& by) {
  const int gx = gridDim.x;
  const int nwg = gx * gridDim.y;
  const int ord = blockIdx.y * gx + blockIdx.x;
  const int q = nwg >> 3, r = nwg & 7;
  const int xcd = ord & 7, local = ord >> 3;
  const int base = xcd < r ? xcd * (q + 1) : r * (q + 1) + (xcd - r) * q;
  const int s = base + local;
  bx = s % gx;
  by = s / gx;
}

// Balanced causal remap: XCD k (= dispatch ord % 8, HW round-robin) owns
// m-rows {k, 15-k}. For scores (live blocks: (k+1)+(16-k)=17 per XCD) and
// PV (sum Keff: (k+1)+(16-k) K-units per XCD) this equalizes work across
// XCDs, which the contiguous-chunk swizzle badly skews under causality.
// Bijective: per plane, XCD k covers (k, 0..gx-1) and (15-k, 0..gx-1).
__device__ __forceinline__ void causal_pair_swz(int& bx, int& by) {
  const int gx = gridDim.x;  // gridDim.y must be 16
  const int ord = blockIdx.y * gx + blockIdx.x;
  const int k = ord & 7;
  const int j = ord >> 3;  // 0 .. 2*gx-1
  by = (j < gx) ? k : 15 - k;
  bx = (j < gx) ? j : j - gx;
}

// fused fp32 -> bf16 for q,k,v (grid.y selects tensor), 8 elems/thread
__global__ __launch_bounds__(256) void cvt3_kernel(
    const float* __restrict__ i0, const float* __restrict__ i1,
    const float* __restrict__ i2, u16* __restrict__ o0, u16* __restrict__ o1,
    u16* __restrict__ o2, int n) {
  const int z = blockIdx.y;
  const float* in = z == 0 ? i0 : (z == 1 ? i1 : i2);
  u16* out = z == 0 ? o0 : (z == 1 ? o1 : o2);
  const int i = (blockIdx.x * 256 + threadIdx.x) * 8;
  if (i >= n) return;
  v4f a = *(const v4f*)(in + i);
  v4f b = *(const v4f*)(in + i + 4);
  v8s o;
#pragma unroll
  for (int j = 0; j < 4; j++) o[j] = (short)f2b(a[j]);
#pragma unroll
  for (int j = 0; j < 4; j++) o[4 + j] = (short)f2b(b[j]);
  *(v8s*)(out + i) = o;
}

// fused fp32 -> bf16 for the 4 weight matrices (grid.y selects)
__global__ __launch_bounds__(256) void cvt4_kernel(
    const float* __restrict__ i0, const float* __restrict__ i1,
    const float* __restrict__ i2, const float* __restrict__ i3,
    u16* __restrict__ o0, u16* __restrict__ o1, u16* __restrict__ o2,
    u16* __restrict__ o3, int n) {
  const int z = blockIdx.y;
  const float* in = z == 0 ? i0 : (z == 1 ? i1 : (z == 2 ? i2 : i3));
  u16* out = z == 0 ? o0 : (z == 1 ? o1 : (z == 2 ? o2 : o3));
  const int i = (blockIdx.x * 256 + threadIdx.x) * 8;
  if (i >= n) return;
  v4f a = *(const v4f*)(in + i);
  v4f b = *(const v4f*)(in + i + 4);
  v8s o;
#pragma unroll
  for (int j = 0; j < 4; j++) o[j] = (short)f2b(a[j]);
#pragma unroll
  for (int j = 0; j < 4; j++) o[4 + j] = (short)f2b(b[j]);
  *(v8s*)(out + i) = o;
}

// Shared GEMM body: C[m,n] = sum_k A[m,k]*B[n,k] (+bias[n]).
// 128x128 tile, BK=64, 4 waves, 32KB LDS.
// LDS layout [128 rows][8 x 16B units], XOR-swizzled: LDS(r, u) holds
// global 16B-chunk (u ^ (r&7)) of row r. global_load_lds writes linearly
// (lane -> base + lane*16B), so the swizzle is applied on the per-lane
// GLOBAL source address and inverted on the ds_read address (rule #21).
// Read conflict: 16 lanes/frag span all 8 units -> 2 lanes/bank-group = free.
template <bool HAS_BIAS, bool CAUSAL_K, bool OUT_F32>
__device__ __forceinline__ void gemm_body(
    const u16* __restrict__ A, int lda, const u16* __restrict__ Bm, int ldb,
    void* __restrict__ Cout_, int ldc, long cbase,
    const float* __restrict__ bias, int K, int m0, int n0) {
  __shared__ u16 ldsA[BM * BK];
  __shared__ u16 ldsB[BN * BK];

  const int tid = threadIdx.x;
  const int wave = tid >> 6, lane = tid & 63;
  const int wm = (wave >> 1) * 64, wn = (wave & 1) * 64;
  const int lrow = lane & 15, quad = lane >> 4;

  v4f acc[4][4];
#pragma unroll
  for (int i = 0; i < 4; i++)
#pragma unroll
    for (int j = 0; j < 4; j++) acc[i][j] = v4f{0.f, 0.f, 0.f, 0.f};

  int Keff = K;
  if (CAUSAL_K) {
    int ke = m0 + BM;
    Keff = ke < K ? ke : K;
  }

  // staging: 4 copies per matrix; copy c covers rows [wave*8 + c*32, +8)
  const int rA = lane >> 3;           // row within the 8-row group
  const int uch = (lane & 7) ^ rA;    // pre-swizzled global 16B-chunk
  const u16* pA = A + (long)(m0 + wave * 8 + rA) * lda + uch * 8;
  const u16* pB = Bm + (long)(n0 + wave * 8 + rA) * ldb + uch * 8;
  u16* dA = ldsA + (wave * 8) * BK;
  u16* dB = ldsB + (wave * 8) * BK;

  for (int k0 = 0; k0 < Keff; k0 += BK) {
#pragma unroll
    for (int c = 0; c < 4; c++) {
      async_copy16(pA + (long)c * 32 * lda + k0, dA + c * 32 * BK);
      async_copy16(pB + (long)c * 32 * ldb + k0, dB + c * 32 * BK);
    }
    __syncthreads();

#pragma unroll
    for (int ks = 0; ks < 2; ks++) {
      v8s af[4], bfr[4];
#pragma unroll
      for (int mt = 0; mt < 4; mt++) {
        const int r = wm + mt * 16 + lrow;
        af[mt] =
            *(const v8s*)&ldsA[r * BK + ((ks * 4 + quad) ^ (r & 7)) * 8];
      }
#pragma unroll
      for (int nt = 0; nt < 4; nt++) {
        const int r = wn + nt * 16 + lrow;
        bfr[nt] =
            *(const v8s*)&ldsB[r * BK + ((ks * 4 + quad) ^ (r & 7)) * 8];
      }
#pragma unroll
      for (int mt = 0; mt < 4; mt++)
#pragma unroll
        for (int nt = 0; nt < 4; nt++)
          acc[mt][nt] = __builtin_amdgcn_mfma_f32_16x16x32_bf16(
              af[mt], bfr[nt], acc[mt][nt], 0, 0, 0);
    }
    __syncthreads();
  }

  // epilogue: C/D layout col = lane&15, row = quad*4 + i (m89-verified)
#pragma unroll
  for (int mt = 0; mt < 4; mt++) {
    const int rowBase = m0 + wm + mt * 16 + quad * 4;
#pragma unroll
    for (int nt = 0; nt < 4; nt++) {
      const int col = n0 + wn + nt * 16 + lrow;
      float bv = 0.f;
      if (HAS_BIAS) bv = bias[col];
#pragma unroll
      for (int i = 0; i < 4; i++) {
        const long idx = cbase + (long)(rowBase + i) * ldc + col;
        const float val = acc[mt][nt][i] + bv;
        if (OUT_F32)
          ((float*)Cout_)[idx] = val;
        else
          ((u16*)Cout_)[idx] = f2b(val);
      }
    }
  }
}

// fused Q/K/V projections: grid.z = {0,1,2} selects (x, W, bias, out)
__global__ __launch_bounds__(256, 4) void qkv_gemm_kernel(
    const u16* __restrict__ a0, const u16* __restrict__ a1,
    const u16* __restrict__ a2, const u16* __restrict__ w0,
    const u16* __restrict__ w1, const u16* __restrict__ w2,
    const float* __restrict__ b0, const float* __restrict__ b1,
    const float* __restrict__ b2, u16* __restrict__ c0, u16* __restrict__ c1,
    u16* __restrict__ c2, int C) {
  const int z = blockIdx.z;
  const u16* A = z == 0 ? a0 : (z == 1 ? a1 : a2);
  const u16* W = z == 0 ? w0 : (z == 1 ? w1 : w2);
  const float* bias = z == 0 ? b0 : (z == 1 ? b1 : b2);
  u16* Cp = z == 0 ? c0 : (z == 1 ? c1 : c2);
  int bx, by;
  xcd_swz(bx, by);
  gemm_body<true, false, false>(A, C, W, C, Cp, C, 0,
                                bias, C, by * BM, bx * BN);
}

// generic batched GEMM (strided over grid.z)
// SWZ: 0 = chunked (dense), 1 = causal pair remap (balanced)
template <bool HAS_BIAS, bool CAUSAL_SKIP, bool CAUSAL_K, bool OUT_F32,
          int SWZ>
__global__ __launch_bounds__(256, 4) void gemm_bt_kernel(
    const u16* __restrict__ A, int lda, long sA,
    const u16* __restrict__ Bm, int ldb, long sB,
    void* __restrict__ Cout_, int ldc, long sC,
    const float* __restrict__ bias, int K) {
  int bx, by;
  if (SWZ == 1)
    causal_pair_swz(bx, by);
  else
    xcd_swz(bx, by);
  const int m0 = by * BM;
  const int n0 = bx * BN;
  if (CAUSAL_SKIP && n0 > m0) return;
  const int z = blockIdx.z;
  gemm_body<HAS_BIAS, CAUSAL_K, OUT_F32>(
      A + (long)z * sA, lda, Bm + (long)z * sB, ldb, Cout_, ldc,
      (long)z * sC, bias, K, m0, n0);
}

// Vp [B][T][C] -> VpT [B][C][T], 64x64 LDS tiles
__global__ __launch_bounds__(256) void transpose_kernel(
    const u16* __restrict__ in, u16* __restrict__ out) {
  __shared__ u16 tile[64][72];
  const int b = blockIdx.z;
  const int d0 = blockIdx.x * 64;  // C dim
  const int t0 = blockIdx.y * 64;  // T dim
  const u16* ip = in + (long)b * 2048 * 1024;
  u16* op = out + (long)b * 1024 * 2048;
  const int tid = threadIdx.x;
  const int tl = tid >> 2;
  const int dl = (tid & 3) * 16;
  const u16* src = ip + (long)(t0 + tl) * 1024 + d0 + dl;
  *(v8s*)&tile[tl][dl] = *(const v8s*)src;
  *(v8s*)&tile[tl][dl + 8] = *(const v8s*)(src + 8);
  __syncthreads();
  const int dd = tid >> 2;
  const int tt = (tid & 3) * 16;
  u16* dst = op + (long)(d0 + dd) * 2048 + t0 + tt;
  v8s o0, o1;
#pragma unroll
  for (int j = 0; j < 8; j++) o0[j] = (short)tile[tt + j][dd];
#pragma unroll
  for (int j = 0; j < 8; j++) o1[j] = (short)tile[tt + 8 + j][dd];
  *(v8s*)dst = o0;
  *(v8s*)(dst + 8) = o1;
}

// in-place causal softmax, one WAVE per row (4 rows/block): no LDS, no
// __syncthreads. Loads only j <= i; stores only j < Lw (what PV reads).
__global__ __launch_bounds__(256) void softmax_kernel(u16* __restrict__ S) {
  const float scale = 0.03125f;  // 1/sqrt(1024)
  const int wave = threadIdx.x >> 6, lane = threadIdx.x & 63;
  const int i = blockIdx.x * 4 + wave, b = blockIdx.y;
  u16* row = S + ((long)b * 2048 + (long)i) * 2048;
  const int Lw = ((i >> 7) + 1) << 7;  // write length (multiple of 128)
  float v[32];
  float m = -1e30f;
#pragma unroll
  for (int c = 0; c < 4; c++) {
    const int jb = c * 512 + lane * 8;
    v8s raw = {0, 0, 0, 0, 0, 0, 0, 0};
    if (jb <= i) raw = *(const v8s*)&row[jb];
#pragma unroll
    for (int jj = 0; jj < 8; jj++) {
      float x = (jb + jj <= i) ? b2f((u16)raw[jj]) * scale : -1e30f;
      v[c * 8 + jj] = x;
      m = fmaxf(m, x);
    }
  }
#pragma unroll
  for (int off = 32; off; off >>= 1) m = fmaxf(m, __shfl_xor(m, off));
  float s = 0.f;
#pragma unroll
  for (int c = 0; c < 4; c++)
#pragma unroll
    for (int jj = 0; jj < 8; jj++) {
      float e = (v[c * 8 + jj] > -1e29f) ? __expf(v[c * 8 + jj] - m) : 0.f;
      v[c * 8 + jj] = e;
      s += e;
    }
#pragma unroll
  for (int off = 32; off; off >>= 1) s += __shfl_xor(s, off);
  const float inv = 1.0f / s;
#pragma unroll
  for (int c = 0; c < 4; c++) {
    const int jb = c * 512 + lane * 8;
    if (jb < Lw) {
      v8s o;
#pragma unroll
      for (int jj = 0; jj < 8; jj++) o[jj] = (short)f2b(v[c * 8 + jj] * inv);
      *(v8s*)&row[jb] = o;
    }
  }
}

extern "C" void kernel_launch(void* const* d_in, const int* in_sizes, int n_in,
                              void* d_out, int out_size, void* d_ws,
                              size_t ws_size, hipStream_t stream) {
  const float* q = (const float*)d_in[0];
  const float* k = (const float*)d_in[1];
  const float* v = (const float*)d_in[2];
  const float* Wq = (const float*)d_in[3];
  const float* bq = (const float*)d_in[4];
  const float* Wk = (const float*)d_in[5];
  const float* bk = (const float*)d_in[6];
  const float* Wv = (const float*)d_in[7];
  const float* bv = (const float*)d_in[8];
  const float* Wff = (const float*)d_in[9];
  const float* bff = (const float*)d_in[10];
  float* out = (float*)d_out;

  const int B = 4, T = 2048, C = 1024, M = B * T;  // M = 8192
  const size_t MC = (size_t)M * C;                 // 8.4M elems
  const size_t CC = (size_t)C * C;                 // 1M elems
  u16* ws = (u16*)d_ws;
  u16* qb = ws;              // [M*C]  (later: S overlays qb+kb)
  u16* kb = qb + MC;
  u16* vb = kb + MC;
  u16* Wqb = vb + MC;        // [C*C] x4
  u16* Wkb = Wqb + CC;
  u16* Wvb = Wkb + CC;
  u16* Wffb = Wvb + CC;
  u16* Qp = Wffb + CC;       // [B][T][C]
  u16* Kp = Qp + MC;
  u16* Vp = Kp + MC;         // reused as attn
  u16* VpT = Vp + MC;        // [B][C][T]
  u16* S = qb;               // [B][T][T], overlays qb+kb (dead by then)
  u16* attn = Vp;            // Vp dead after transpose

  dim3 blk(256);
  // fp32 -> bf16 conversions (2 fused launches)
  cvt3_kernel<<<dim3((int)(MC / 2048), 3), blk, 0, stream>>>(
      q, k, v, qb, kb, vb, (int)MC);
  cvt4_kernel<<<dim3((int)(CC / 2048), 4), blk, 0, stream>>>(
      Wq, Wk, Wv, Wff, Wqb, Wkb, Wvb, Wffb, (int)CC);

  // fused Q/K/V projections (grid 8 x 64 x 3 = 1536 blocks)
  qkv_gemm_kernel<<<dim3(C / BN, M / BM, 3), blk, 0, stream>>>(
      qb, kb, vb, Wqb, Wkb, Wvb, bq, bk, bv, Qp, Kp, Vp, C);
  // V transpose for the PV GEMM
  transpose_kernel<<<dim3(C / 64, T / 64, B), blk, 0, stream>>>(Vp, VpT);
  // scores S = Qp @ Kp^T per batch (balanced causal remap)
  gemm_bt_kernel<false, true, false, false, 1>
      <<<dim3(T / BN, T / BM, B), blk, 0, stream>>>(
          Qp, C, (long)T * C, Kp, C, (long)T * C, S, T, (long)T * T,
          nullptr, C);
  // causal softmax in-place -> P  (one wave per row)
  softmax_kernel<<<dim3(T / 4, B), blk, 0, stream>>>(S);
  // attn = P @ V per batch (K limited to diagonal; balanced causal remap)
  gemm_bt_kernel<false, false, true, false, 1>
      <<<dim3(C / BN, T / BM, B), blk, 0, stream>>>(
          S, T, (long)T * T, VpT, T, (long)C * T, attn, C, (long)T * C,
          nullptr, T);
  // out = attn @ Wff.T + bff  (fp32 out)
  gemm_bt_kernel<true, false, false, true, 0>
      <<<dim3(C / BN, M / BM, 1), blk, 0, stream>>>(
          attn, C, 0, Wffb, C, 0, out, C, 0, bff, C);
}